// Round 6
// baseline (415.427 us; speedup 1.0000x reference)
//
#include <hip/hip_runtime.h>
#include <cstdio>

// MinGRU: B=4, T=4096, D=1024, Di=2048
#define T_LEN 4096
#define B_SZ  4
#define D_IN  1024
#define DI    2048
#define MM    16384   // B*T
#define NC2   128     // scan chunks (length 32)
#define CHL2  32      // scan chunk length

typedef __attribute__((ext_vector_type(8))) __bf16 bf16x8;
typedef __attribute__((ext_vector_type(4))) float  f32x4;
typedef __attribute__((ext_vector_type(8))) unsigned short u16x8;

__device__ __forceinline__ unsigned short f2bf(float f){
  unsigned u = __builtin_bit_cast(unsigned, f);
  u += 0x7fffu + ((u >> 16) & 1u);   // round-to-nearest-even (inputs never NaN)
  return (unsigned short)(u >> 16);
}
__device__ __forceinline__ float bf2f_lo(unsigned u){
  return __builtin_bit_cast(float, u << 16);
}
__device__ __forceinline__ float bf2f_hi(unsigned u){
  return __builtin_bit_cast(float, u & 0xffff0000u);
}
__device__ __forceinline__ float bf2f_s(unsigned short s){
  return __builtin_bit_cast(float, (unsigned)s << 16);
}

__device__ __forceinline__ void async16(void* lds, const void* g){
  __builtin_amdgcn_global_load_lds((const __attribute__((address_space(1))) void*)g,
                                   (__attribute__((address_space(3))) void*)lds, 16, 0, 0);
}

// ---- merged prep: fp32->bf16 convert of x + both weight transposes ----
template<int PERM>
__device__ __forceinline__ void transpose_body(const float* __restrict__ src,
                                               unsigned short* __restrict__ dst,
                                               int n0, int k0, int SK, int SN,
                                               float (*tile)[65], int tid){
  #pragma unroll
  for(int it=0; it<16; it++){
    int idx = it*256 + tid;
    int kk = idx>>6, nn = idx&63;
    int n = n0+nn;
    int col = PERM ? (((n>>5)<<4) + (n&15) + ((n&16)?2048:0)) : n;
    tile[kk][nn] = src[(size_t)(k0+kk)*SN + col];
  }
  __syncthreads();
  #pragma unroll
  for(int it=0; it<16; it++){
    int idx = it*256 + tid;
    int nn = idx>>6, kk = idx&63;
    dst[(size_t)(n0+nn)*SK + k0+kk] = f2bf(tile[kk][nn]);
  }
}

__global__ __launch_bounds__(256) void k_prep(const float* __restrict__ x,
                                              unsigned short* __restrict__ xb,
                                              const float* __restrict__ Whg,
                                              unsigned short* __restrict__ wt,
                                              const float* __restrict__ Wout,
                                              unsigned short* __restrict__ wo){
  __shared__ float tile[64][65];
  int bid = blockIdx.x, tid = threadIdx.x;
  if(bid < 8192){
    size_t t = (size_t)bid*256 + tid;
    const float4* xi = (const float4*)x;
    float4 a = xi[2*t], b = xi[2*t+1];
    u16x8 o;
    o[0]=f2bf(a.x); o[1]=f2bf(a.y); o[2]=f2bf(a.z); o[3]=f2bf(a.w);
    o[4]=f2bf(b.x); o[5]=f2bf(b.y); o[6]=f2bf(b.z); o[7]=f2bf(b.w);
    ((u16x8*)xb)[t] = o;
  } else if(bid < 9216){
    int j = bid - 8192;
    transpose_body<1>(Whg, wt, (j&63)*64, (j>>6)*64, 1024, 4096, tile, tid);
  } else {
    int j = bid - 9216;
    transpose_body<0>(Wout, wo, (j&15)*64, (j>>4)*64, 2048, 1024, tile, tid);
  }
}

// ---- bf16 MFMA GEMM body, A(M,K) row-major, Bt(N,K) row-major, 128x128 tile,
// BK=64.  PROVEN m97-class structure (851 TF GEMM1, MfmaUtil+VALUBusy=95%).
// LDS row stride = 64 shorts (128 B); rank-8 XOR swizzle: LDS slot s of row r
// holds global 8-short chunk s ^ (r&7) -> quarter-wave b128 reads hit all 32
// banks 2-way (free); staging stays one 128B segment per 8 lanes.
// R3 lesson: XCD blockIdx swizzle TRIPLED GEMM1 FETCH (151->422 MB) -> the
// orig%8 XCD-assignment assumption is wrong on this chip; default dispatch
// order already has locality (consecutive blocks share an A-panel). BOTH
// GEMMs now use the identity mapping (R6: removed from GEMM2 too).
// EPI=0: fp32 C0 store.  EPI=1: hidden/gate interleaved cols -> c=sigmoid(-gate),
// v=sigmoid(gate)*g(hidden), pair-packed dword stores (shfl_xor lane pairing),
// plus fused 32-row chunk affine summaries -> Ap/Vp (bf16). Summary-LDS uses
// stride 72 floats (72%32=8 -> banks 8*quad+cl, <=2-way = free; was stride 64
// = 4-way, the stable 524288 conflict count).
template<int EPI>
__device__ __forceinline__ void gemm_body(unsigned short* lsA, unsigned short* lsB,
            const unsigned short* __restrict__ A, const unsigned short* __restrict__ Bt,
            float* __restrict__ C0, unsigned* __restrict__ U0,
            unsigned* __restrict__ U1, unsigned short* __restrict__ Ap,
            unsigned short* __restrict__ Vp, int M, int N, int K){
  int tid  = threadIdx.x;
  int lane = tid & 63, wave = tid >> 6;
  int wm = wave >> 1, wn = wave & 1;
  int cl = lane & 15, quad = lane >> 4;

  int m0 = blockIdx.y * 128, n0 = blockIdx.x * 128;

  f32x4 acc[4][4];
  #pragma unroll
  for(int i=0;i<4;i++)
    #pragma unroll
    for(int j=0;j<4;j++) acc[i][j] = (f32x4){0.f,0.f,0.f,0.f};

  // staging: thread -> rows (tid>>3)+32*it, LDS slot tid&7,
  // global chunk fetched = (tid&7) ^ ((tid>>3)&7)
  int g = (tid&7) ^ ((tid>>3)&7);
  const unsigned short* gA = A  + (size_t)(m0 + (tid>>3))*K + g*8;
  const unsigned short* gB = Bt + (size_t)(n0 + (tid>>3))*K + g*8;
  unsigned short* dA = lsA + tid*8;
  unsigned short* dB = lsB + tid*8;

  for(int k0=0; k0<K; k0+=64){
    #pragma unroll
    for(int it=0; it<4; it++){
      async16(dA + it*2048, gA + (size_t)(it*32)*K + k0);
      async16(dB + it*2048, gB + (size_t)(it*32)*K + k0);
    }
    __syncthreads();
    #pragma unroll
    for(int kh=0; kh<2; kh++){
      bf16x8 fa[4], fb[4];
      int sl = ((kh<<2)|quad);
      #pragma unroll
      for(int t2=0;t2<4;t2++){
        int ra = wm*64 + t2*16 + cl;
        int rb = wn*64 + t2*16 + cl;
        fa[t2] = *(const bf16x8*)&lsA[ra*64 + (sl^(cl&7))*8];
        fb[t2] = *(const bf16x8*)&lsB[rb*64 + (sl^(cl&7))*8];
      }
      #pragma unroll
      for(int i=0;i<4;i++)
        #pragma unroll
        for(int j=0;j<4;j++)
          acc[i][j] = __builtin_amdgcn_mfma_f32_16x16x32_bf16(fa[i], fb[j], acc[i][j], 0, 0, 0);
    }
    __syncthreads();
  }

  if(EPI==0){
    #pragma unroll
    for(int i=0;i<4;i++)
      #pragma unroll
      for(int j=0;j<4;j++){
        int n = n0 + wn*64 + j*16 + cl;
        #pragma unroll
        for(int r=0;r<4;r++){
          int m = m0 + wm*64 + i*16 + quad*4 + r;
          C0[(size_t)m*N + n] = acc[i][j][r];
        }
      }
  } else {
    // Fused scan summary: per-lane 4-row partial maps -> seg-major LDS
    // (32 segs of 4 rows, stride 72 floats), then 256 threads compose 8 segs
    // each into four 32-row chunk summaries (bf16).
    float* lA_f = (float*)lsA;   // [seg(32)][stride 72] = 9.2 KB (fits 16 KB)
    float* lV_f = (float*)lsB;
    int ibase = ((n0 + wn*64) >> 1) + cl;
    int odd = cl & 1;
    #pragma unroll
    for(int i=0;i<4;i++)
      #pragma unroll
      for(int p=0;p<2;p++){
        f32x4 hh = acc[i][2*p], gg = acc[i][2*p+1];
        int ii = ibase + p*16;
        float pa = 1.f, pv = 0.f;
        #pragma unroll
        for(int r=0;r<4;r++){
          int m = m0 + wm*64 + i*16 + quad*4 + r;   // flat (b*T+t)
          float gate = gg[r], hid = hh[r];
          float e  = __expf(gate);
          float cc = 1.f/(1.f + e);                 // sigmoid(-gate)
          float z  = (gate > 80.f) ? 1.f : e*cc;    // sigmoid(gate)
          float gv = (hid >= 0.f) ? (hid + 0.5f) : (1.f/(1.f + __expf(-hid)));
          float vv = z*gv;
          // pair-pack: lane cl^1 holds the adjacent channel of the same row
          float ccp = __shfl_xor(cc, 1, 64);
          float vvp = __shfl_xor(vv, 1, 64);
          unsigned wlo = odd ? (unsigned)f2bf(vvp) : (unsigned)f2bf(cc);
          unsigned whi = odd ? (unsigned)f2bf(vv)  : (unsigned)f2bf(ccp);
          unsigned* dst = odd ? U1 : U0;
          dst[((size_t)m*DI + (ii & ~1)) >> 1] = wlo | (whi << 16);
          pa *= cc;
          pv = fmaf(cc, pv, vv);
        }
        int seg = wm*16 + i*4 + quad;
        int chl = wn*32 + p*16 + cl;
        lA_f[seg*72 + chl] = pa;
        lV_f[seg*72 + chl] = pv;
      }
    __syncthreads();
    {
      int ch = tid & 63, q = tid >> 6;              // q = 32-row chunk in block
      float Ac = 1.f, Vc = 0.f;
      #pragma unroll
      for(int s=0; s<8; s++){
        int idx = (q*8 + s)*72 + ch;
        float a = lA_f[idx], v = lV_f[idx];
        Ac *= a;
        Vc = fmaf(a, Vc, v);
      }
      int b = m0 >> 12;
      int ch32 = ((m0 & 4095) >> 5) + q;            // 32-row chunk index in batch
      size_t o = (size_t)(b*NC2 + ch32)*DI + (n0 >> 1) + ch;
      Ap[o] = f2bf(Ac); Vp[o] = f2bf(Vc);
    }
  }
}

// Distinct kernel names so rocprof rows separate GEMM1 vs GEMM2.
__global__ __launch_bounds__(256, 2)
void k_gemmHG(const unsigned short* __restrict__ A, const unsigned short* __restrict__ Bt,
              unsigned* __restrict__ U0, unsigned* __restrict__ U1,
              unsigned short* __restrict__ Ap, unsigned short* __restrict__ Vp,
              int M, int N, int K){
  __shared__ unsigned short lsA[128*64];   // 16 KB
  __shared__ unsigned short lsB[128*64];   // 16 KB
  gemm_body<1>(lsA, lsB, A, Bt, nullptr, U0, U1, Ap, Vp, M, N, K);
}

__global__ __launch_bounds__(256, 2)
void k_gemmOUT(const unsigned short* __restrict__ A, const unsigned short* __restrict__ Bt,
               float* __restrict__ C0, int M, int N, int K){
  // padded to 55296 B total -> exactly 2 blocks/CU -> 1024 blocks = 2 full
  // zero-tail rounds (R3: this netted a measurable win)
  __shared__ unsigned short lsA[19456];    // main loop uses first 16 KB
  __shared__ unsigned short lsB[128*64];   // 16 KB
  gemm_body<0>(lsA, lsB, A, Bt, C0, nullptr, nullptr, nullptr, nullptr, M, N, K);
}

// ---- scan phase B (v2): two-level latency-parallel affine scan.
// 65536 threads; thread = (channel, group of 16 chunks).
//   1) issue all 32 independent loads at once, fold group affine (A,V) in regs
//   2) per-channel sequential compose of the 8 group affines via LDS (exact
//      left-to-right order preserved -> same math as before up to fp32 assoc.)
//   3) replay 16 chunks from group-start h in registers, store hin (bf16).
// Serial-dependent memory chain: 128 -> ~1.  (R5: -15us vs serial version)
__global__ __launch_bounds__(256) void k_scanB(const float* __restrict__ prev,
                                               unsigned short* __restrict__ Ap,
                                               const unsigned short* __restrict__ Vp){
  int tid = threadIdx.x;
  int cl = tid & 31;                        // channel within block
  int g  = tid >> 5;                        // group 0..7 (16 chunks each)
  int chan = blockIdx.x*32 + cl;            // 0..8191 = B*DI
  int i = chan & (DI-1); int b = chan >> 11;
  size_t o0 = (size_t)(b*NC2 + g*16)*DI + i;
  float a[16], v[16];
  #pragma unroll
  for(int j=0;j<16;j++){
    a[j] = bf2f_s(Ap[o0 + (size_t)j*DI]);
    v[j] = bf2f_s(Vp[o0 + (size_t)j*DI]);
  }
  float A = 1.f, V = 0.f;
  #pragma unroll
  for(int j=0;j<16;j++){ A *= a[j]; V = fmaf(a[j], V, v[j]); }
  __shared__ float sA[8][32], sV[8][32], sH[8][32];
  sA[g][cl] = A; sV[g][cl] = V;
  __syncthreads();
  if(g == 0){
    float h = fmaxf(prev[chan], 1e-8f);     // h_0
    #pragma unroll
    for(int j=0;j<8;j++){
      sH[j][cl] = h;                        // h at START of group j
      h = fmaf(sA[j][cl], h, sV[j][cl]);
    }
  }
  __syncthreads();
  float h = sH[g][cl];
  #pragma unroll
  for(int j=0;j<16;j++){
    Ap[o0 + (size_t)j*DI] = f2bf(h);        // hin for this chunk
    h = fmaf(a[j], h, v[j]);
  }
}

// ---- scan phase C: recurrence per 32-chunk; h (bf16) overwrites v in place;
//      next_hidden (fp32) from last chunk. uint4-vectorized: one thread owns
//      8 channels (16B per stream per step) -> 4x fewer mem ops than dword ver.
__global__ __launch_bounds__(256) void k_scanC(const uint4* __restrict__ cp,
                                               uint4* __restrict__ vp,
                                               const uint4* __restrict__ hinp,
                                               float* __restrict__ nh){
  int t = blockIdx.x*256 + threadIdx.x;     // 131072 = B*NC2*DI/8
  int i8 = t & (DI/8 - 1);                  // uint4 index within row (256)
  int ch = (t >> 8) & (NC2-1);
  int b  = t >> 15;
  size_t base = ((size_t)(b*T_LEN + ch*CHL2))*(DI/8) + i8;
  uint4 hp = hinp[(size_t)(b*NC2 + ch)*(DI/8) + i8];
  float h0 = bf2f_lo(hp.x), h1 = bf2f_hi(hp.x);
  float h2 = bf2f_lo(hp.y), h3 = bf2f_hi(hp.y);
  float h4 = bf2f_lo(hp.z), h5 = bf2f_hi(hp.z);
  float h6 = bf2f_lo(hp.w), h7 = bf2f_hi(hp.w);
  #pragma unroll 4
  for(int s=0; s<CHL2; s++){
    uint4 cu = cp[base], vu = vp[base];
    h0 = fmaf(bf2f_lo(cu.x), h0, bf2f_lo(vu.x));
    h1 = fmaf(bf2f_hi(cu.x), h1, bf2f_hi(vu.x));
    h2 = fmaf(bf2f_lo(cu.y), h2, bf2f_lo(vu.y));
    h3 = fmaf(bf2f_hi(cu.y), h3, bf2f_hi(vu.y));
    h4 = fmaf(bf2f_lo(cu.z), h4, bf2f_lo(vu.z));
    h5 = fmaf(bf2f_hi(cu.z), h5, bf2f_hi(vu.z));
    h6 = fmaf(bf2f_lo(cu.w), h6, bf2f_lo(vu.w));
    h7 = fmaf(bf2f_hi(cu.w), h7, bf2f_hi(vu.w));
    uint4 o;
    o.x = (unsigned)f2bf(h0) | ((unsigned)f2bf(h1) << 16);
    o.y = (unsigned)f2bf(h2) | ((unsigned)f2bf(h3) << 16);
    o.z = (unsigned)f2bf(h4) | ((unsigned)f2bf(h5) << 16);
    o.w = (unsigned)f2bf(h6) | ((unsigned)f2bf(h7) << 16);
    vp[base] = o;
    base += DI/8;
  }
  if(ch == NC2-1){
    float* d = nh + (size_t)b*DI + 8*i8;
    d[0]=h0; d[1]=h1; d[2]=h2; d[3]=h3; d[4]=h4; d[5]=h5; d[6]=h6; d[7]=h7;
  }
}

extern "C" void kernel_launch(void* const* d_in, const int* in_sizes, int n_in,
                              void* d_out, int out_size, void* d_ws, size_t ws_size,
                              hipStream_t stream){
  const float* x    = (const float*)d_in[0];   // (4,4096,1024)
  const float* prev = (const float*)d_in[1];   // (4,2048)
  const float* Whg  = (const float*)d_in[2];   // (1024,4096)
  const float* Wout = (const float*)d_in[3];   // (2048,1024)
  float* out = (float*)d_out;                  // (4,4096,1024) fp32
  float* nh  = out + (size_t)MM*D_IN;          // (4,2048) fp32

  // workspace layout (total 117,440,512 B — proven available)
  const size_t NEED = 117440512;
  if(ws_size < NEED){
    fprintf(stderr, "kernel_launch: ws_size=%zu < needed %zu — aborting launch\n",
            ws_size, NEED);
    return;
  }
  char* ws = (char*)d_ws;
  unsigned short* xb = (unsigned short*)(ws);                    // 33,554,432 B bf16 x
  unsigned short* wt = (unsigned short*)(ws + 33554432);         //  8,388,608 B (4096x1024)
  unsigned short* wo = (unsigned short*)(ws + 41943040);         //  4,194,304 B (1024x2048)
  unsigned short* v  = (unsigned short*)(ws + 46137344);         // 67,108,864 B bf16 v (h in-place)
  unsigned short* Ap = (unsigned short*)(ws + 113246208);        // 2,097,152 B bf16 (hin in-place)
  unsigned short* Vp = (unsigned short*)(ws + 115343360);        // 2,097,152 B bf16
  // c (bf16, 33.5M elems = 64 MB) parked in d_out's `out` region (dead until GEMM2)
  unsigned* c = (unsigned*)d_out;

  k_prep<<<9728, 256, 0, stream>>>(x, xb, Whg, wt, Wout, wo);

  // GEMM1: (16384x1024)x(1024x4096) -> c (d_out), v (ws), fused scanA -> Ap/Vp
  k_gemmHG<<<dim3(32,128), 256, 0, stream>>>(xb, wt, c, (unsigned*)v,
                                             Ap, Vp, MM, 2*DI, D_IN);

  k_scanB<<<256,  256, 0, stream>>>(prev, Ap, Vp);
  k_scanC<<<512,  256, 0, stream>>>((const uint4*)c, (uint4*)v,
                                    (const uint4*)Ap, nh);

  // GEMM2: (16384x2048)x(2048x1024) -> out  (overwrites the c region last)
  k_gemmOUT<<<dim3(8,128), 256, 0, stream>>>(v, wo, out, MM, D_IN, DI);
}

// Round 7
// 400.587 us; speedup vs baseline: 1.0370x; 1.0370x over previous
//
#include <hip/hip_runtime.h>
#include <cstdio>

// MinGRU: B=4, T=4096, D=1024, Di=2048
#define T_LEN 4096
#define B_SZ  4
#define D_IN  1024
#define DI    2048
#define MM    16384   // B*T
#define NC2   128     // scan chunks (length 32)
#define CHL2  32      // scan chunk length

typedef __attribute__((ext_vector_type(8))) __bf16 bf16x8;
typedef __attribute__((ext_vector_type(4))) float  f32x4;
typedef __attribute__((ext_vector_type(8))) unsigned short u16x8;

__device__ __forceinline__ unsigned short f2bf(float f){
  unsigned u = __builtin_bit_cast(unsigned, f);
  u += 0x7fffu + ((u >> 16) & 1u);   // round-to-nearest-even (inputs never NaN)
  return (unsigned short)(u >> 16);
}
__device__ __forceinline__ float bf2f_lo(unsigned u){
  return __builtin_bit_cast(float, u << 16);
}
__device__ __forceinline__ float bf2f_hi(unsigned u){
  return __builtin_bit_cast(float, u & 0xffff0000u);
}
__device__ __forceinline__ float bf2f_s(unsigned short s){
  return __builtin_bit_cast(float, (unsigned)s << 16);
}

__device__ __forceinline__ void async16(void* lds, const void* g){
  __builtin_amdgcn_global_load_lds((const __attribute__((address_space(1))) void*)g,
                                   (__attribute__((address_space(3))) void*)lds, 16, 0, 0);
}

// ---- merged prep: fp32->bf16 convert of x + both weight transposes ----
template<int PERM>
__device__ __forceinline__ void transpose_body(const float* __restrict__ src,
                                               unsigned short* __restrict__ dst,
                                               int n0, int k0, int SK, int SN,
                                               float (*tile)[65], int tid){
  #pragma unroll
  for(int it=0; it<16; it++){
    int idx = it*256 + tid;
    int kk = idx>>6, nn = idx&63;
    int n = n0+nn;
    int col = PERM ? (((n>>5)<<4) + (n&15) + ((n&16)?2048:0)) : n;
    tile[kk][nn] = src[(size_t)(k0+kk)*SN + col];
  }
  __syncthreads();
  #pragma unroll
  for(int it=0; it<16; it++){
    int idx = it*256 + tid;
    int nn = idx>>6, kk = idx&63;
    dst[(size_t)(n0+nn)*SK + k0+kk] = f2bf(tile[kk][nn]);
  }
}

__global__ __launch_bounds__(256) void k_prep(const float* __restrict__ x,
                                              unsigned short* __restrict__ xb,
                                              const float* __restrict__ Whg,
                                              unsigned short* __restrict__ wt,
                                              const float* __restrict__ Wout,
                                              unsigned short* __restrict__ wo){
  __shared__ float tile[64][65];
  int bid = blockIdx.x, tid = threadIdx.x;
  if(bid < 8192){
    size_t t = (size_t)bid*256 + tid;
    const float4* xi = (const float4*)x;
    float4 a = xi[2*t], b = xi[2*t+1];
    u16x8 o;
    o[0]=f2bf(a.x); o[1]=f2bf(a.y); o[2]=f2bf(a.z); o[3]=f2bf(a.w);
    o[4]=f2bf(b.x); o[5]=f2bf(b.y); o[6]=f2bf(b.z); o[7]=f2bf(b.w);
    ((u16x8*)xb)[t] = o;
  } else if(bid < 9216){
    int j = bid - 8192;
    transpose_body<1>(Whg, wt, (j&63)*64, (j>>6)*64, 1024, 4096, tile, tid);
  } else {
    int j = bid - 9216;
    transpose_body<0>(Wout, wo, (j&15)*64, (j>>4)*64, 2048, 1024, tile, tid);
  }
}

// ---- bf16 MFMA GEMM body, A(M,K) row-major, Bt(N,K) row-major, 128x128 tile,
// BK=64.  PROVEN m97-class structure (851 TF GEMM1, MfmaUtil+VALUBusy=95%).
// LDS row stride = 64 shorts (128 B); rank-8 XOR swizzle: LDS slot s of row r
// holds global 8-short chunk s ^ (r&7) -> quarter-wave b128 reads hit all 32
// banks 2-way (free); staging stays one 128B segment per 8 lanes.
// Block-mapping policy (A/B/A-tested R3-R7):
//   GEMM1 (32-wide grid): IDENTITY. XCD swizzle tripled FETCH (151->422 MB, +7us).
//   GEMM2 (8-wide grid): XCD SWIZZLE. Removing it cost +24us (R6); its 512KB
//   A-panel is reused by only 8 consecutive blocks, which default dispatch
//   order scatters across L2s. Swizzle value depends on grid aspect ratio.
// EPI=0: fp32 C0 store.  EPI=1: hidden/gate interleaved cols -> c=sigmoid(-gate),
// v=sigmoid(gate)*g(hidden), pair-packed dword stores (shfl_xor lane pairing),
// plus fused 32-row chunk affine summaries -> Ap/Vp (bf16).
// (Note: the stable 524288 SQ_LDS_BANK_CONFLICT is a fixed ~128-cycle/block
// cost NOT from the summary LDS — stride 64->72 change was conflict-neutral.)
template<int EPI>
__device__ __forceinline__ void gemm_body(unsigned short* lsA, unsigned short* lsB,
            const unsigned short* __restrict__ A, const unsigned short* __restrict__ Bt,
            float* __restrict__ C0, unsigned* __restrict__ U0,
            unsigned* __restrict__ U1, unsigned short* __restrict__ Ap,
            unsigned short* __restrict__ Vp, int M, int N, int K){
  int tid  = threadIdx.x;
  int lane = tid & 63, wave = tid >> 6;
  int wm = wave >> 1, wn = wave & 1;
  int cl = lane & 15, quad = lane >> 4;

  int m0, n0;
  if(EPI==1){
    // identity mapping (default dispatch order already L2/L3-local; R3 evidence)
    m0 = blockIdx.y * 128; n0 = blockIdx.x * 128;
  } else {
    // XCD-aware bijective swizzle (nwg % 8 == 0; gx pow2) — R6 removal cost +24us
    int gx = gridDim.x;
    int nwg = gx * gridDim.y;
    int orig = blockIdx.y * gx + blockIdx.x;
    int swz = (orig & 7) * (nwg >> 3) + (orig >> 3);
    int lg = 31 - __clz(gx);
    int bx = swz & (gx - 1), by = swz >> lg;
    m0 = by * 128; n0 = bx * 128;
  }

  f32x4 acc[4][4];
  #pragma unroll
  for(int i=0;i<4;i++)
    #pragma unroll
    for(int j=0;j<4;j++) acc[i][j] = (f32x4){0.f,0.f,0.f,0.f};

  // staging: thread -> rows (tid>>3)+32*it, LDS slot tid&7,
  // global chunk fetched = (tid&7) ^ ((tid>>3)&7)
  int g = (tid&7) ^ ((tid>>3)&7);
  const unsigned short* gA = A  + (size_t)(m0 + (tid>>3))*K + g*8;
  const unsigned short* gB = Bt + (size_t)(n0 + (tid>>3))*K + g*8;
  unsigned short* dA = lsA + tid*8;
  unsigned short* dB = lsB + tid*8;

  for(int k0=0; k0<K; k0+=64){
    #pragma unroll
    for(int it=0; it<4; it++){
      async16(dA + it*2048, gA + (size_t)(it*32)*K + k0);
      async16(dB + it*2048, gB + (size_t)(it*32)*K + k0);
    }
    __syncthreads();
    #pragma unroll
    for(int kh=0; kh<2; kh++){
      bf16x8 fa[4], fb[4];
      int sl = ((kh<<2)|quad);
      #pragma unroll
      for(int t2=0;t2<4;t2++){
        int ra = wm*64 + t2*16 + cl;
        int rb = wn*64 + t2*16 + cl;
        fa[t2] = *(const bf16x8*)&lsA[ra*64 + (sl^(cl&7))*8];
        fb[t2] = *(const bf16x8*)&lsB[rb*64 + (sl^(cl&7))*8];
      }
      #pragma unroll
      for(int i=0;i<4;i++)
        #pragma unroll
        for(int j=0;j<4;j++)
          acc[i][j] = __builtin_amdgcn_mfma_f32_16x16x32_bf16(fa[i], fb[j], acc[i][j], 0, 0, 0);
    }
    __syncthreads();
  }

  if(EPI==0){
    #pragma unroll
    for(int i=0;i<4;i++)
      #pragma unroll
      for(int j=0;j<4;j++){
        int n = n0 + wn*64 + j*16 + cl;
        #pragma unroll
        for(int r=0;r<4;r++){
          int m = m0 + wm*64 + i*16 + quad*4 + r;
          C0[(size_t)m*N + n] = acc[i][j][r];
        }
      }
  } else {
    // Fused scan summary: per-lane 4-row partial maps -> seg-major LDS
    // (32 segs of 4 rows, stride 72 floats), then 256 threads compose 8 segs
    // each into four 32-row chunk summaries (bf16).
    float* lA_f = (float*)lsA;   // [seg(32)][stride 72] = 9.2 KB (fits 16 KB)
    float* lV_f = (float*)lsB;
    int ibase = ((n0 + wn*64) >> 1) + cl;
    int odd = cl & 1;
    #pragma unroll
    for(int i=0;i<4;i++)
      #pragma unroll
      for(int p=0;p<2;p++){
        f32x4 hh = acc[i][2*p], gg = acc[i][2*p+1];
        int ii = ibase + p*16;
        float pa = 1.f, pv = 0.f;
        #pragma unroll
        for(int r=0;r<4;r++){
          int m = m0 + wm*64 + i*16 + quad*4 + r;   // flat (b*T+t)
          float gate = gg[r], hid = hh[r];
          float e  = __expf(gate);
          float cc = 1.f/(1.f + e);                 // sigmoid(-gate)
          float z  = (gate > 80.f) ? 1.f : e*cc;    // sigmoid(gate)
          float gv = (hid >= 0.f) ? (hid + 0.5f) : (1.f/(1.f + __expf(-hid)));
          float vv = z*gv;
          // pair-pack: lane cl^1 holds the adjacent channel of the same row
          float ccp = __shfl_xor(cc, 1, 64);
          float vvp = __shfl_xor(vv, 1, 64);
          unsigned wlo = odd ? (unsigned)f2bf(vvp) : (unsigned)f2bf(cc);
          unsigned whi = odd ? (unsigned)f2bf(vv)  : (unsigned)f2bf(ccp);
          unsigned* dst = odd ? U1 : U0;
          dst[((size_t)m*DI + (ii & ~1)) >> 1] = wlo | (whi << 16);
          pa *= cc;
          pv = fmaf(cc, pv, vv);
        }
        int seg = wm*16 + i*4 + quad;
        int chl = wn*32 + p*16 + cl;
        lA_f[seg*72 + chl] = pa;
        lV_f[seg*72 + chl] = pv;
      }
    __syncthreads();
    {
      int ch = tid & 63, q = tid >> 6;              // q = 32-row chunk in block
      float Ac = 1.f, Vc = 0.f;
      #pragma unroll
      for(int s=0; s<8; s++){
        int idx = (q*8 + s)*72 + ch;
        float a = lA_f[idx], v = lV_f[idx];
        Ac *= a;
        Vc = fmaf(a, Vc, v);
      }
      int b = m0 >> 12;
      int ch32 = ((m0 & 4095) >> 5) + q;            // 32-row chunk index in batch
      size_t o = (size_t)(b*NC2 + ch32)*DI + (n0 >> 1) + ch;
      Ap[o] = f2bf(Ac); Vp[o] = f2bf(Vc);
    }
  }
}

// Distinct kernel names so rocprof rows separate GEMM1 vs GEMM2.
__global__ __launch_bounds__(256, 2)
void k_gemmHG(const unsigned short* __restrict__ A, const unsigned short* __restrict__ Bt,
              unsigned* __restrict__ U0, unsigned* __restrict__ U1,
              unsigned short* __restrict__ Ap, unsigned short* __restrict__ Vp,
              int M, int N, int K){
  __shared__ unsigned short lsA[128*64];   // 16 KB
  __shared__ unsigned short lsB[128*64];   // 16 KB
  gemm_body<1>(lsA, lsB, A, Bt, nullptr, U0, U1, Ap, Vp, M, N, K);
}

__global__ __launch_bounds__(256, 2)
void k_gemmOUT(const unsigned short* __restrict__ A, const unsigned short* __restrict__ Bt,
               float* __restrict__ C0, int M, int N, int K){
  // padded to 55296 B total -> exactly 2 blocks/CU -> 1024 blocks = 2 full
  // zero-tail rounds (R3: measurable win; R6: removing the swizzle cost +24us)
  __shared__ unsigned short lsA[19456];    // main loop uses first 16 KB
  __shared__ unsigned short lsB[128*64];   // 16 KB
  gemm_body<0>(lsA, lsB, A, Bt, C0, nullptr, nullptr, nullptr, nullptr, M, N, K);
}

// ---- scan phase B (v2): two-level latency-parallel affine scan.
// 65536 threads; thread = (channel, group of 16 chunks).
//   1) issue all 32 independent loads at once, fold group affine (A,V) in regs
//   2) per-channel sequential compose of the 8 group affines via LDS (exact
//      left-to-right order preserved -> same math as before up to fp32 assoc.)
//   3) replay 16 chunks from group-start h in registers, store hin (bf16).
// Serial-dependent memory chain: 128 -> ~1.  (R5: -15us vs serial version)
__global__ __launch_bounds__(256) void k_scanB(const float* __restrict__ prev,
                                               unsigned short* __restrict__ Ap,
                                               const unsigned short* __restrict__ Vp){
  int tid = threadIdx.x;
  int cl = tid & 31;                        // channel within block
  int g  = tid >> 5;                        // group 0..7 (16 chunks each)
  int chan = blockIdx.x*32 + cl;            // 0..8191 = B*DI
  int i = chan & (DI-1); int b = chan >> 11;
  size_t o0 = (size_t)(b*NC2 + g*16)*DI + i;
  float a[16], v[16];
  #pragma unroll
  for(int j=0;j<16;j++){
    a[j] = bf2f_s(Ap[o0 + (size_t)j*DI]);
    v[j] = bf2f_s(Vp[o0 + (size_t)j*DI]);
  }
  float A = 1.f, V = 0.f;
  #pragma unroll
  for(int j=0;j<16;j++){ A *= a[j]; V = fmaf(a[j], V, v[j]); }
  __shared__ float sA[8][32], sV[8][32], sH[8][32];
  sA[g][cl] = A; sV[g][cl] = V;
  __syncthreads();
  if(g == 0){
    float h = fmaxf(prev[chan], 1e-8f);     // h_0
    #pragma unroll
    for(int j=0;j<8;j++){
      sH[j][cl] = h;                        // h at START of group j
      h = fmaf(sA[j][cl], h, sV[j][cl]);
    }
  }
  __syncthreads();
  float h = sH[g][cl];
  #pragma unroll
  for(int j=0;j<16;j++){
    Ap[o0 + (size_t)j*DI] = f2bf(h);        // hin for this chunk
    h = fmaf(a[j], h, v[j]);
  }
}

// ---- scan phase C: recurrence per 32-chunk; h (bf16) overwrites v in place;
//      next_hidden (fp32) from last chunk. uint4-vectorized: one thread owns
//      8 channels (16B per stream per step) -> 4x fewer mem ops than dword ver.
__global__ __launch_bounds__(256) void k_scanC(const uint4* __restrict__ cp,
                                               uint4* __restrict__ vp,
                                               const uint4* __restrict__ hinp,
                                               float* __restrict__ nh){
  int t = blockIdx.x*256 + threadIdx.x;     // 131072 = B*NC2*DI/8
  int i8 = t & (DI/8 - 1);                  // uint4 index within row (256)
  int ch = (t >> 8) & (NC2-1);
  int b  = t >> 15;
  size_t base = ((size_t)(b*T_LEN + ch*CHL2))*(DI/8) + i8;
  uint4 hp = hinp[(size_t)(b*NC2 + ch)*(DI/8) + i8];
  float h0 = bf2f_lo(hp.x), h1 = bf2f_hi(hp.x);
  float h2 = bf2f_lo(hp.y), h3 = bf2f_hi(hp.y);
  float h4 = bf2f_lo(hp.z), h5 = bf2f_hi(hp.z);
  float h6 = bf2f_lo(hp.w), h7 = bf2f_hi(hp.w);
  #pragma unroll 4
  for(int s=0; s<CHL2; s++){
    uint4 cu = cp[base], vu = vp[base];
    h0 = fmaf(bf2f_lo(cu.x), h0, bf2f_lo(vu.x));
    h1 = fmaf(bf2f_hi(cu.x), h1, bf2f_hi(vu.x));
    h2 = fmaf(bf2f_lo(cu.y), h2, bf2f_lo(vu.y));
    h3 = fmaf(bf2f_hi(cu.y), h3, bf2f_hi(vu.y));
    h4 = fmaf(bf2f_lo(cu.z), h4, bf2f_lo(vu.z));
    h5 = fmaf(bf2f_hi(cu.z), h5, bf2f_hi(vu.z));
    h6 = fmaf(bf2f_lo(cu.w), h6, bf2f_lo(vu.w));
    h7 = fmaf(bf2f_hi(cu.w), h7, bf2f_hi(vu.w));
    uint4 o;
    o.x = (unsigned)f2bf(h0) | ((unsigned)f2bf(h1) << 16);
    o.y = (unsigned)f2bf(h2) | ((unsigned)f2bf(h3) << 16);
    o.z = (unsigned)f2bf(h4) | ((unsigned)f2bf(h5) << 16);
    o.w = (unsigned)f2bf(h6) | ((unsigned)f2bf(h7) << 16);
    vp[base] = o;
    base += DI/8;
  }
  if(ch == NC2-1){
    float* d = nh + (size_t)b*DI + 8*i8;
    d[0]=h0; d[1]=h1; d[2]=h2; d[3]=h3; d[4]=h4; d[5]=h5; d[6]=h6; d[7]=h7;
  }
}

extern "C" void kernel_launch(void* const* d_in, const int* in_sizes, int n_in,
                              void* d_out, int out_size, void* d_ws, size_t ws_size,
                              hipStream_t stream){
  const float* x    = (const float*)d_in[0];   // (4,4096,1024)
  const float* prev = (const float*)d_in[1];   // (4,2048)
  const float* Whg  = (const float*)d_in[2];   // (1024,4096)
  const float* Wout = (const float*)d_in[3];   // (2048,1024)
  float* out = (float*)d_out;                  // (4,4096,1024) fp32
  float* nh  = out + (size_t)MM*D_IN;          // (4,2048) fp32

  // workspace layout (total 117,440,512 B — proven available)
  const size_t NEED = 117440512;
  if(ws_size < NEED){
    fprintf(stderr, "kernel_launch: ws_size=%zu < needed %zu — aborting launch\n",
            ws_size, NEED);
    return;
  }
  char* ws = (char*)d_ws;
  unsigned short* xb = (unsigned short*)(ws);                    // 33,554,432 B bf16 x
  unsigned short* wt = (unsigned short*)(ws + 33554432);         //  8,388,608 B (4096x1024)
  unsigned short* wo = (unsigned short*)(ws + 41943040);         //  4,194,304 B (1024x2048)
  unsigned short* v  = (unsigned short*)(ws + 46137344);         // 67,108,864 B bf16 v (h in-place)
  unsigned short* Ap = (unsigned short*)(ws + 113246208);        // 2,097,152 B bf16 (hin in-place)
  unsigned short* Vp = (unsigned short*)(ws + 115343360);        // 2,097,152 B bf16
  // c (bf16, 33.5M elems = 64 MB) parked in d_out's `out` region (dead until GEMM2)
  unsigned* c = (unsigned*)d_out;

  k_prep<<<9728, 256, 0, stream>>>(x, xb, Whg, wt, Wout, wo);

  // GEMM1: (16384x1024)x(1024x4096) -> c (d_out), v (ws), fused scanA -> Ap/Vp
  k_gemmHG<<<dim3(32,128), 256, 0, stream>>>(xb, wt, c, (unsigned*)v,
                                             Ap, Vp, MM, 2*DI, D_IN);

  k_scanB<<<256,  256, 0, stream>>>(prev, Ap, Vp);
  k_scanC<<<512,  256, 0, stream>>>((const uint4*)c, (uint4*)v,
                                    (const uint4*)Ap, nh);

  // GEMM2: (16384x2048)x(2048x1024) -> out  (overwrites the c region last)
  k_gemmOUT<<<dim3(8,128), 256, 0, stream>>>(v, wo, out, MM, D_IN, DI);
}

// Round 8
// 390.254 us; speedup vs baseline: 1.0645x; 1.0265x over previous
//
#include <hip/hip_runtime.h>
#include <cstdio>

// MinGRU: B=4, T=4096, D=1024, Di=2048
#define T_LEN 4096
#define B_SZ  4
#define D_IN  1024
#define DI    2048
#define MM    16384   // B*T
#define NC2   128     // scan chunks (length 32)
#define CHL2  32      // scan chunk length

typedef __attribute__((ext_vector_type(8))) __bf16 bf16x8;
typedef __attribute__((ext_vector_type(4))) float  f32x4;
typedef __attribute__((ext_vector_type(8))) unsigned short u16x8;

__device__ __forceinline__ unsigned short f2bf(float f){
  unsigned u = __builtin_bit_cast(unsigned, f);
  u += 0x7fffu + ((u >> 16) & 1u);   // round-to-nearest-even (inputs never NaN)
  return (unsigned short)(u >> 16);
}
__device__ __forceinline__ float bf2f_lo(unsigned u){
  return __builtin_bit_cast(float, u << 16);
}
__device__ __forceinline__ float bf2f_hi(unsigned u){
  return __builtin_bit_cast(float, u & 0xffff0000u);
}
__device__ __forceinline__ float bf2f_s(unsigned short s){
  return __builtin_bit_cast(float, (unsigned)s << 16);
}

__device__ __forceinline__ void async16(void* lds, const void* g){
  __builtin_amdgcn_global_load_lds((const __attribute__((address_space(1))) void*)g,
                                   (__attribute__((address_space(3))) void*)lds, 16, 0, 0);
}

// ---- merged prep: fp32->bf16 convert of x + both weight transposes ----
template<int PERM>
__device__ __forceinline__ void transpose_body(const float* __restrict__ src,
                                               unsigned short* __restrict__ dst,
                                               int n0, int k0, int SK, int SN,
                                               float (*tile)[65], int tid){
  #pragma unroll
  for(int it=0; it<16; it++){
    int idx = it*256 + tid;
    int kk = idx>>6, nn = idx&63;
    int n = n0+nn;
    int col = PERM ? (((n>>5)<<4) + (n&15) + ((n&16)?2048:0)) : n;
    tile[kk][nn] = src[(size_t)(k0+kk)*SN + col];
  }
  __syncthreads();
  #pragma unroll
  for(int it=0; it<16; it++){
    int idx = it*256 + tid;
    int nn = idx>>6, kk = idx&63;
    dst[(size_t)(n0+nn)*SK + k0+kk] = f2bf(tile[kk][nn]);
  }
}

__global__ __launch_bounds__(256) void k_prep(const float* __restrict__ x,
                                              unsigned short* __restrict__ xb,
                                              const float* __restrict__ Whg,
                                              unsigned short* __restrict__ wt,
                                              const float* __restrict__ Wout,
                                              unsigned short* __restrict__ wo){
  __shared__ float tile[64][65];
  int bid = blockIdx.x, tid = threadIdx.x;
  if(bid < 8192){
    size_t t = (size_t)bid*256 + tid;
    const float4* xi = (const float4*)x;
    float4 a = xi[2*t], b = xi[2*t+1];
    u16x8 o;
    o[0]=f2bf(a.x); o[1]=f2bf(a.y); o[2]=f2bf(a.z); o[3]=f2bf(a.w);
    o[4]=f2bf(b.x); o[5]=f2bf(b.y); o[6]=f2bf(b.z); o[7]=f2bf(b.w);
    ((u16x8*)xb)[t] = o;
  } else if(bid < 9216){
    int j = bid - 8192;
    transpose_body<1>(Whg, wt, (j&63)*64, (j>>6)*64, 1024, 4096, tile, tid);
  } else {
    int j = bid - 9216;
    transpose_body<0>(Wout, wo, (j&15)*64, (j>>4)*64, 2048, 1024, tile, tid);
  }
}

// ---- GEMM1: bf16 MFMA, A(M,K) row-major, Bt(N,K) row-major, 128x128 tile,
// BK=64.  PROVEN m97-class structure (851 TF, MfmaUtil+VALUBusy=95%).
// LDS row stride = 64 shorts (128 B); rank-8 XOR swizzle: LDS slot s of row r
// holds global 8-short chunk s ^ (r&7) -> quarter-wave b128 reads hit all 32
// banks 2-way (free); staging stays one 128B segment per 8 lanes.
// Block-mapping policy (A/B/A-tested R3-R7):
//   GEMM1 (32-wide grid): IDENTITY. XCD swizzle tripled FETCH (151->422 MB).
//   GEMM2 (8-wide grid): XCD SWIZZLE. Removing it cost +24us (R6).
// Epilogue: hidden/gate interleaved cols -> c=sigmoid(-gate),
// v=sigmoid(gate)*g(hidden), pair-packed dword stores (shfl_xor lane pairing),
// plus fused 32-row chunk affine summaries -> Ap/Vp (bf16).
__global__ __launch_bounds__(256, 2)
void k_gemmHG(const unsigned short* __restrict__ A, const unsigned short* __restrict__ Bt,
              unsigned* __restrict__ U0, unsigned* __restrict__ U1,
              unsigned short* __restrict__ Ap, unsigned short* __restrict__ Vp,
              int M, int N, int K){
  __shared__ unsigned short lsA[128*64];   // 16 KB
  __shared__ unsigned short lsB[128*64];   // 16 KB
  int tid  = threadIdx.x;
  int lane = tid & 63, wave = tid >> 6;
  int wm = wave >> 1, wn = wave & 1;
  int cl = lane & 15, quad = lane >> 4;

  int m0 = blockIdx.y * 128, n0 = blockIdx.x * 128;   // identity mapping

  f32x4 acc[4][4];
  #pragma unroll
  for(int i=0;i<4;i++)
    #pragma unroll
    for(int j=0;j<4;j++) acc[i][j] = (f32x4){0.f,0.f,0.f,0.f};

  // staging: thread -> rows (tid>>3)+32*it, LDS slot tid&7,
  // global chunk fetched = (tid&7) ^ ((tid>>3)&7)
  int g = (tid&7) ^ ((tid>>3)&7);
  const unsigned short* gA = A  + (size_t)(m0 + (tid>>3))*K + g*8;
  const unsigned short* gB = Bt + (size_t)(n0 + (tid>>3))*K + g*8;
  unsigned short* dA = lsA + tid*8;
  unsigned short* dB = lsB + tid*8;

  for(int k0=0; k0<K; k0+=64){
    #pragma unroll
    for(int it=0; it<4; it++){
      async16(dA + it*2048, gA + (size_t)(it*32)*K + k0);
      async16(dB + it*2048, gB + (size_t)(it*32)*K + k0);
    }
    __syncthreads();
    #pragma unroll
    for(int kh=0; kh<2; kh++){
      bf16x8 fa[4], fb[4];
      int sl = ((kh<<2)|quad);
      #pragma unroll
      for(int t2=0;t2<4;t2++){
        int ra = wm*64 + t2*16 + cl;
        int rb = wn*64 + t2*16 + cl;
        fa[t2] = *(const bf16x8*)&lsA[ra*64 + (sl^(cl&7))*8];
        fb[t2] = *(const bf16x8*)&lsB[rb*64 + (sl^(cl&7))*8];
      }
      #pragma unroll
      for(int i=0;i<4;i++)
        #pragma unroll
        for(int j=0;j<4;j++)
          acc[i][j] = __builtin_amdgcn_mfma_f32_16x16x32_bf16(fa[i], fb[j], acc[i][j], 0, 0, 0);
    }
    __syncthreads();
  }

  // Fused scan summary epilogue
  float* lA_f = (float*)lsA;   // [seg(32)][stride 72] = 9.2 KB (fits 16 KB)
  float* lV_f = (float*)lsB;
  int ibase = ((n0 + wn*64) >> 1) + cl;
  int odd = cl & 1;
  #pragma unroll
  for(int i=0;i<4;i++)
    #pragma unroll
    for(int p=0;p<2;p++){
      f32x4 hh = acc[i][2*p], gg = acc[i][2*p+1];
      int ii = ibase + p*16;
      float pa = 1.f, pv = 0.f;
      #pragma unroll
      for(int r=0;r<4;r++){
        int m = m0 + wm*64 + i*16 + quad*4 + r;   // flat (b*T+t)
        float gate = gg[r], hid = hh[r];
        float e  = __expf(gate);
        float cc = 1.f/(1.f + e);                 // sigmoid(-gate)
        float z  = (gate > 80.f) ? 1.f : e*cc;    // sigmoid(gate)
        float gv = (hid >= 0.f) ? (hid + 0.5f) : (1.f/(1.f + __expf(-hid)));
        float vv = z*gv;
        // pair-pack: lane cl^1 holds the adjacent channel of the same row
        float ccp = __shfl_xor(cc, 1, 64);
        float vvp = __shfl_xor(vv, 1, 64);
        unsigned wlo = odd ? (unsigned)f2bf(vvp) : (unsigned)f2bf(cc);
        unsigned whi = odd ? (unsigned)f2bf(vv)  : (unsigned)f2bf(ccp);
        unsigned* dst = odd ? U1 : U0;
        dst[((size_t)m*DI + (ii & ~1)) >> 1] = wlo | (whi << 16);
        pa *= cc;
        pv = fmaf(cc, pv, vv);
      }
      int seg = wm*16 + i*4 + quad;
      int chl = wn*32 + p*16 + cl;
      lA_f[seg*72 + chl] = pa;
      lV_f[seg*72 + chl] = pv;
    }
  __syncthreads();
  {
    int ch = tid & 63, q = tid >> 6;              // q = 32-row chunk in block
    float Ac = 1.f, Vc = 0.f;
    #pragma unroll
    for(int s=0; s<8; s++){
      int idx = (q*8 + s)*72 + ch;
      float a = lA_f[idx], v = lV_f[idx];
      Ac *= a;
      Vc = fmaf(a, Vc, v);
    }
    int b = m0 >> 12;
    int ch32 = ((m0 & 4095) >> 5) + q;            // 32-row chunk index in batch
    size_t o = (size_t)(b*NC2 + ch32)*DI + (n0 >> 1) + ch;
    Ap[o] = f2bf(Ac); Vp[o] = f2bf(Vc);
  }
}

// ---- GEMM2 (R8): 256x128 tile, BK=64, 4 waves (2M x 2N, wave tile 128x64,
// acc[8][4]).  Same proven inner-loop invariants as GEMM1 (all row offsets
// 0 mod 8 -> identical XOR-swizzle math).  Grid 8x64 = 512 blocks; LDS padded
// to 55296 B caps residency at 2 blocks/CU -> 512 = 256x2 perfectly balanced,
// ONE round, zero tail (was 1024 blocks / 2 synchronized rounds).  Per K-step:
// 64 MFMA/wave vs 12 staging loads (vs 32:8) -> 33% less barrier+staging
// overhead per FLOP.  XCD swizzle kept (R6: removing cost +24us).
__global__ __launch_bounds__(256, 2)
void k_gemmOUT(const unsigned short* __restrict__ A, const unsigned short* __restrict__ Bt,
               float* __restrict__ C0, int M, int N, int K){
  __shared__ unsigned short lsA[19456];    // data: 16384 shorts (256r x 64k) = 32 KB; pad -> 2/CU
  __shared__ unsigned short lsB[128*64];   // 16 KB
  int tid  = threadIdx.x;
  int lane = tid & 63, wave = tid >> 6;
  int wm = wave >> 1, wn = wave & 1;       // wave tile 128(M) x 64(N)
  int cl = lane & 15, quad = lane >> 4;

  // XCD-aware bijective swizzle (nwg=512 %8==0; gx=8 pow2)
  int gx = gridDim.x;
  int nwg = gx * gridDim.y;
  int orig = blockIdx.y * gx + blockIdx.x;
  int swz = (orig & 7) * (nwg >> 3) + (orig >> 3);
  int bx = swz & (gx - 1), by = swz >> 3;
  int m0 = by * 256, n0 = bx * 128;

  f32x4 acc[8][4];
  #pragma unroll
  for(int i=0;i<8;i++)
    #pragma unroll
    for(int j=0;j<4;j++) acc[i][j] = (f32x4){0.f,0.f,0.f,0.f};

  // staging: thread -> rows (tid>>3)+32*it (A: it 0..7 = 256 rows; B: it 0..3),
  // LDS slot tid&7, global chunk = (tid&7)^((tid>>3)&7)  (row+32 preserves r&7)
  int g = (tid&7) ^ ((tid>>3)&7);
  const unsigned short* gA = A  + (size_t)(m0 + (tid>>3))*K + g*8;
  const unsigned short* gB = Bt + (size_t)(n0 + (tid>>3))*K + g*8;
  unsigned short* dA = lsA + tid*8;
  unsigned short* dB = lsB + tid*8;

  for(int k0=0; k0<K; k0+=64){
    #pragma unroll
    for(int it=0; it<8; it++)
      async16(dA + it*2048, gA + (size_t)(it*32)*K + k0);
    #pragma unroll
    for(int it=0; it<4; it++)
      async16(dB + it*2048, gB + (size_t)(it*32)*K + k0);
    __syncthreads();
    #pragma unroll
    for(int kh=0; kh<2; kh++){
      bf16x8 fa[8], fb[4];
      int sl = ((kh<<2)|quad);
      #pragma unroll
      for(int t2=0;t2<4;t2++){
        int rb = wn*64 + t2*16 + cl;
        fb[t2] = *(const bf16x8*)&lsB[rb*64 + (sl^(cl&7))*8];
      }
      #pragma unroll
      for(int t2=0;t2<8;t2++){
        int ra = wm*128 + t2*16 + cl;
        fa[t2] = *(const bf16x8*)&lsA[ra*64 + (sl^(cl&7))*8];
      }
      #pragma unroll
      for(int i=0;i<8;i++)
        #pragma unroll
        for(int j=0;j<4;j++)
          acc[i][j] = __builtin_amdgcn_mfma_f32_16x16x32_bf16(fa[i], fb[j], acc[i][j], 0, 0, 0);
    }
    __syncthreads();
  }

  #pragma unroll
  for(int i=0;i<8;i++)
    #pragma unroll
    for(int j=0;j<4;j++){
      int n = n0 + wn*64 + j*16 + cl;
      #pragma unroll
      for(int r=0;r<4;r++){
        int m = m0 + wm*128 + i*16 + quad*4 + r;
        C0[(size_t)m*N + n] = acc[i][j][r];
      }
    }
}

// ---- scan phase B (v2): two-level latency-parallel affine scan.
// 65536 threads; thread = (channel, group of 16 chunks).
//   1) issue all 32 independent loads at once, fold group affine (A,V) in regs
//   2) per-channel sequential compose of the 8 group affines via LDS (exact
//      left-to-right order preserved -> same math as before up to fp32 assoc.)
//   3) replay 16 chunks from group-start h in registers, store hin (bf16).
// Serial-dependent memory chain: 128 -> ~1.  (R5: -15us vs serial version)
__global__ __launch_bounds__(256) void k_scanB(const float* __restrict__ prev,
                                               unsigned short* __restrict__ Ap,
                                               const unsigned short* __restrict__ Vp){
  int tid = threadIdx.x;
  int cl = tid & 31;                        // channel within block
  int g  = tid >> 5;                        // group 0..7 (16 chunks each)
  int chan = blockIdx.x*32 + cl;            // 0..8191 = B*DI
  int i = chan & (DI-1); int b = chan >> 11;
  size_t o0 = (size_t)(b*NC2 + g*16)*DI + i;
  float a[16], v[16];
  #pragma unroll
  for(int j=0;j<16;j++){
    a[j] = bf2f_s(Ap[o0 + (size_t)j*DI]);
    v[j] = bf2f_s(Vp[o0 + (size_t)j*DI]);
  }
  float A = 1.f, V = 0.f;
  #pragma unroll
  for(int j=0;j<16;j++){ A *= a[j]; V = fmaf(a[j], V, v[j]); }
  __shared__ float sA[8][32], sV[8][32], sH[8][32];
  sA[g][cl] = A; sV[g][cl] = V;
  __syncthreads();
  if(g == 0){
    float h = fmaxf(prev[chan], 1e-8f);     // h_0
    #pragma unroll
    for(int j=0;j<8;j++){
      sH[j][cl] = h;                        // h at START of group j
      h = fmaf(sA[j][cl], h, sV[j][cl]);
    }
  }
  __syncthreads();
  float h = sH[g][cl];
  #pragma unroll
  for(int j=0;j<16;j++){
    Ap[o0 + (size_t)j*DI] = f2bf(h);        // hin for this chunk
    h = fmaf(a[j], h, v[j]);
  }
}

// ---- scan phase C: recurrence per 32-chunk; h (bf16) overwrites v in place;
//      next_hidden (fp32) from last chunk. uint4-vectorized: one thread owns
//      8 channels (16B per stream per step) -> 4x fewer mem ops than dword ver.
__global__ __launch_bounds__(256) void k_scanC(const uint4* __restrict__ cp,
                                               uint4* __restrict__ vp,
                                               const uint4* __restrict__ hinp,
                                               float* __restrict__ nh){
  int t = blockIdx.x*256 + threadIdx.x;     // 131072 = B*NC2*DI/8
  int i8 = t & (DI/8 - 1);                  // uint4 index within row (256)
  int ch = (t >> 8) & (NC2-1);
  int b  = t >> 15;
  size_t base = ((size_t)(b*T_LEN + ch*CHL2))*(DI/8) + i8;
  uint4 hp = hinp[(size_t)(b*NC2 + ch)*(DI/8) + i8];
  float h0 = bf2f_lo(hp.x), h1 = bf2f_hi(hp.x);
  float h2 = bf2f_lo(hp.y), h3 = bf2f_hi(hp.y);
  float h4 = bf2f_lo(hp.z), h5 = bf2f_hi(hp.z);
  float h6 = bf2f_lo(hp.w), h7 = bf2f_hi(hp.w);
  #pragma unroll 4
  for(int s=0; s<CHL2; s++){
    uint4 cu = cp[base], vu = vp[base];
    h0 = fmaf(bf2f_lo(cu.x), h0, bf2f_lo(vu.x));
    h1 = fmaf(bf2f_hi(cu.x), h1, bf2f_hi(vu.x));
    h2 = fmaf(bf2f_lo(cu.y), h2, bf2f_lo(vu.y));
    h3 = fmaf(bf2f_hi(cu.y), h3, bf2f_hi(vu.y));
    h4 = fmaf(bf2f_lo(cu.z), h4, bf2f_lo(vu.z));
    h5 = fmaf(bf2f_hi(cu.z), h5, bf2f_hi(vu.z));
    h6 = fmaf(bf2f_lo(cu.w), h6, bf2f_lo(vu.w));
    h7 = fmaf(bf2f_hi(cu.w), h7, bf2f_hi(vu.w));
    uint4 o;
    o.x = (unsigned)f2bf(h0) | ((unsigned)f2bf(h1) << 16);
    o.y = (unsigned)f2bf(h2) | ((unsigned)f2bf(h3) << 16);
    o.z = (unsigned)f2bf(h4) | ((unsigned)f2bf(h5) << 16);
    o.w = (unsigned)f2bf(h6) | ((unsigned)f2bf(h7) << 16);
    vp[base] = o;
    base += DI/8;
  }
  if(ch == NC2-1){
    float* d = nh + (size_t)b*DI + 8*i8;
    d[0]=h0; d[1]=h1; d[2]=h2; d[3]=h3; d[4]=h4; d[5]=h5; d[6]=h6; d[7]=h7;
  }
}

extern "C" void kernel_launch(void* const* d_in, const int* in_sizes, int n_in,
                              void* d_out, int out_size, void* d_ws, size_t ws_size,
                              hipStream_t stream){
  const float* x    = (const float*)d_in[0];   // (4,4096,1024)
  const float* prev = (const float*)d_in[1];   // (4,2048)
  const float* Whg  = (const float*)d_in[2];   // (1024,4096)
  const float* Wout = (const float*)d_in[3];   // (2048,1024)
  float* out = (float*)d_out;                  // (4,4096,1024) fp32
  float* nh  = out + (size_t)MM*D_IN;          // (4,2048) fp32

  // workspace layout (total 117,440,512 B — proven available)
  const size_t NEED = 117440512;
  if(ws_size < NEED){
    fprintf(stderr, "kernel_launch: ws_size=%zu < needed %zu — aborting launch\n",
            ws_size, NEED);
    return;
  }
  char* ws = (char*)d_ws;
  unsigned short* xb = (unsigned short*)(ws);                    // 33,554,432 B bf16 x
  unsigned short* wt = (unsigned short*)(ws + 33554432);         //  8,388,608 B (4096x1024)
  unsigned short* wo = (unsigned short*)(ws + 41943040);         //  4,194,304 B (1024x2048)
  unsigned short* v  = (unsigned short*)(ws + 46137344);         // 67,108,864 B bf16 v (h in-place)
  unsigned short* Ap = (unsigned short*)(ws + 113246208);        // 2,097,152 B bf16 (hin in-place)
  unsigned short* Vp = (unsigned short*)(ws + 115343360);        // 2,097,152 B bf16
  // c (bf16, 33.5M elems = 64 MB) parked in d_out's `out` region (dead until GEMM2)
  unsigned* c = (unsigned*)d_out;

  k_prep<<<9728, 256, 0, stream>>>(x, xb, Whg, wt, Wout, wo);

  // GEMM1: (16384x1024)x(1024x4096) -> c (d_out), v (ws), fused scanA -> Ap/Vp
  k_gemmHG<<<dim3(32,128), 256, 0, stream>>>(xb, wt, c, (unsigned*)v,
                                             Ap, Vp, MM, 2*DI, D_IN);

  k_scanB<<<256,  256, 0, stream>>>(prev, Ap, Vp);
  k_scanC<<<512,  256, 0, stream>>>((const uint4*)c, (uint4*)v,
                                    (const uint4*)Ap, nh);

  // GEMM2: (16384x2048)x(2048x1024) -> out  (overwrites the c region last)
  k_gemmOUT<<<dim3(8,64), 256, 0, stream>>>(v, wo, out, MM, D_IN, DI);
}